// Round 1
// baseline (526.585 us; speedup 1.0000x reference)
//
#include <hip/hip_runtime.h>

#define NB 32       // batch
#define NS 2048     // seq
#define ND 1536     // hidden dim
#define NG 150      // groups
#define NK 9        // merge size
#define NR 32       // remove-list len
#define MAXT 150    // max tokens

// ---------------------------------------------------------------------------
// Kernel 1: per-sample integer phase.
// Computes per-group valid count (idx != -1 and not in valid remove list),
// keep flags, prefix-sum ranks, and builds:
//   src_map[i][p] = group index feeding output position p (or -1 => zero row)
//   cnt_map[i][p] = that group's valid count
//   attn_out[i][p] = 1.0f for the right-aligned kept slots, else 0.0f
// ---------------------------------------------------------------------------
__global__ __launch_bounds__(256)
void build_map_kernel(const int* __restrict__ patch_idx,   // [B,G,K]
                      const int* __restrict__ rem,         // [B,R]
                      int* __restrict__ src_map,           // [B,MAXT]
                      int* __restrict__ cnt_map,           // [B,MAXT]
                      float* __restrict__ attn_out)        // [B,MAXT] (as f32)
{
    const int i = blockIdx.x;
    const int t = threadIdx.x;

    __shared__ int rem_s[NR];
    __shared__ int keep_s[NG];
    __shared__ int cnt_s[NG];
    __shared__ int nkept_s;

    if (t < NR) rem_s[t] = rem[i * NR + t];
    __syncthreads();

    if (t < NG) {
        int cnt = 0;
#pragma unroll
        for (int k = 0; k < NK; ++k) {
            int v = patch_idx[(i * NG + t) * NK + k];
            bool m = (v != -1);
            if (m) {
                for (int r = 0; r < NR; ++r) {
                    int rv = rem_s[r];
                    if (rv != -1 && rv == v) { m = false; break; }
                }
            }
            cnt += m ? 1 : 0;
        }
        cnt_s[t] = cnt;
        keep_s[t] = (cnt > 0) ? 1 : 0;
    }
    __syncthreads();

    if (t == 0) {
        int n = 0;
        for (int g = 0; g < NG; ++g) n += keep_s[g];
        nkept_s = n;
        int rank = 0;
        for (int g = 0; g < NG; ++g) {
            if (keep_s[g]) {
                int pos = MAXT - n + rank;          // right-aligned
                src_map[i * MAXT + pos] = g;
                cnt_map[i * MAXT + pos] = cnt_s[g];
                ++rank;
            }
        }
    }
    __syncthreads();

    const int n = nkept_s;
    if (t < MAXT) {
        if (t < MAXT - n) src_map[i * MAXT + t] = -1;   // zero rows (no overlap with scatter)
        attn_out[i * MAXT + t] = (t >= MAXT - n) ? 1.0f : 0.0f;
    }
}

// ---------------------------------------------------------------------------
// Kernel 2: gather + mean. One block per (sample, output position).
// 384 threads: thread t owns float4 column t (384*4 = 1536 = D).
// Sums ALL K gathered rows (faithful to reference: gathered.sum(axis=1)
// ignores the mask), scales by 1/max(cnt,1).
// ---------------------------------------------------------------------------
__global__ __launch_bounds__(384)
void gather_mean_kernel(const float* __restrict__ h,        // [B,S,D]
                        const int* __restrict__ pr,         // [B,2]
                        const int* __restrict__ patch_idx,  // [B,G,K]
                        const int* __restrict__ src_map,    // [B,MAXT]
                        const int* __restrict__ cnt_map,    // [B,MAXT]
                        float* __restrict__ out)            // [B,MAXT,D]
{
    const int b = blockIdx.x;             // [0, B*MAXT)
    const int i = b / MAXT;
    const int t = threadIdx.x;

    float4* outp = (float4*)(out + (size_t)b * ND);

    const int g = src_map[b];
    if (g < 0) {
        outp[t] = make_float4(0.f, 0.f, 0.f, 0.f);
        return;
    }

    __shared__ int   gidx_s[NK];
    __shared__ float inv_s;

    if (t < NK) {
        int start = pr[i * 2 + 0];
        int end   = pr[i * 2 + 1];
        int v = patch_idx[(i * NG + g) * NK + t];
        gidx_s[t] = (v >= 0) ? (start + v) : (end + 1 + v);   // -1 wraps to last row
    }
    if (t == NK) {
        int c = cnt_map[b];
        inv_s = 1.0f / (float)(c > 1 ? c : 1);
    }
    __syncthreads();

    const float4* hb = (const float4*)(h + (size_t)i * NS * ND);

    float4 acc = make_float4(0.f, 0.f, 0.f, 0.f);
#pragma unroll
    for (int k = 0; k < NK; ++k) {
        const float4 v = hb[(size_t)gidx_s[k] * (ND / 4) + t];
        acc.x += v.x; acc.y += v.y; acc.z += v.z; acc.w += v.w;
    }
    const float inv = inv_s;
    outp[t] = make_float4(acc.x * inv, acc.y * inv, acc.z * inv, acc.w * inv);
}

// ---------------------------------------------------------------------------
extern "C" void kernel_launch(void* const* d_in, const int* in_sizes, int n_in,
                              void* d_out, int out_size, void* d_ws, size_t ws_size,
                              hipStream_t stream)
{
    const float* h    = (const float*)d_in[0];   // hidden_states [B,S,D] f32
    // d_in[1] attention_mask (unused), d_in[2] image_grid_thw (unused)
    const int* pr     = (const int*)d_in[3];     // patch_range_list [B,2]
    const int* pidx   = (const int*)d_in[4];     // patch_indices_list_list [B,G,K]
    const int* rem    = (const int*)d_in[5];     // remove_index_list_list [B,R]

    float* out      = (float*)d_out;                         // [B,MAXT,D]
    float* attn_out = out + (size_t)NB * MAXT * ND;          // [B,MAXT] as f32

    int* src_map = (int*)d_ws;                               // [B*MAXT]
    int* cnt_map = src_map + NB * MAXT;                      // [B*MAXT]

    build_map_kernel<<<NB, 256, 0, stream>>>(pidx, rem, src_map, cnt_map, attn_out);
    gather_mean_kernel<<<NB * MAXT, 384, 0, stream>>>(h, pr, pidx, src_map, cnt_map, out);
}

// Round 3
// 522.890 us; speedup vs baseline: 1.0071x; 1.0071x over previous
//
#include <hip/hip_runtime.h>

#define NB 32       // batch
#define NS 2048     // seq
#define ND 1536     // hidden dim
#define NG 150      // groups
#define NK 9        // merge size
#define NR 32       // remove-list len
#define MAXT 150    // max tokens

typedef float v4f __attribute__((ext_vector_type(4)));

// ---------------------------------------------------------------------------
// Kernel 1: per-sample integer phase.
//   src_map[i][p] = group index feeding output position p (or -1 => zero row)
//   cnt_map[i][p] = that group's valid count
//   attn_out[i][p] = 1.0f for the right-aligned kept slots, else 0.0f
// ---------------------------------------------------------------------------
__global__ __launch_bounds__(256)
void build_map_kernel(const int* __restrict__ patch_idx,   // [B,G,K]
                      const int* __restrict__ rem,         // [B,R]
                      int* __restrict__ src_map,           // [B,MAXT]
                      int* __restrict__ cnt_map,           // [B,MAXT]
                      float* __restrict__ attn_out)        // [B,MAXT] (as f32)
{
    const int i = blockIdx.x;
    const int t = threadIdx.x;

    __shared__ int rem_s[NR];
    __shared__ int keep_s[NG];
    __shared__ int cnt_s[NG];
    __shared__ int nkept_s;

    if (t < NR) rem_s[t] = rem[i * NR + t];
    __syncthreads();

    if (t < NG) {
        int cnt = 0;
#pragma unroll
        for (int k = 0; k < NK; ++k) {
            int v = patch_idx[(i * NG + t) * NK + k];
            bool m = (v != -1);
            if (m) {
                for (int r = 0; r < NR; ++r) {
                    int rv = rem_s[r];
                    if (rv != -1 && rv == v) { m = false; break; }
                }
            }
            cnt += m ? 1 : 0;
        }
        cnt_s[t] = cnt;
        keep_s[t] = (cnt > 0) ? 1 : 0;
    }
    __syncthreads();

    if (t == 0) {
        int n = 0;
        for (int g = 0; g < NG; ++g) n += keep_s[g];
        nkept_s = n;
        int rank = 0;
        for (int g = 0; g < NG; ++g) {
            if (keep_s[g]) {
                int pos = MAXT - n + rank;          // right-aligned
                src_map[i * MAXT + pos] = g;
                cnt_map[i * MAXT + pos] = cnt_s[g];
                ++rank;
            }
        }
    }
    __syncthreads();

    const int n = nkept_s;
    if (t < MAXT) {
        if (t < MAXT - n) src_map[i * MAXT + t] = -1;   // zero rows
        attn_out[i * MAXT + t] = (t >= MAXT - n) ? 1.0f : 0.0f;
    }
}

// ---------------------------------------------------------------------------
// Kernel 2: gather + mean. One block per (sample, output position).
// 384 threads: thread t owns float4 column t (384*4 = 1536 = D).
// All control values are forced scalar (readfirstlane) so index/metadata
// loads become s_loads and the 9 row loads issue back-to-back off SGPR
// bases with a simple voffset = t*16. No LDS, no barriers.
// Sums ALL K gathered rows (faithful: gathered.sum(axis=1) ignores mask),
// scales by 1/max(cnt,1).
// ---------------------------------------------------------------------------
__global__ __launch_bounds__(384)
void gather_mean_kernel(const float* __restrict__ h,        // [B,S,D]
                        const int* __restrict__ pr,         // [B,2]
                        const int* __restrict__ patch_idx,  // [B,G,K]
                        const int* __restrict__ src_map,    // [B,MAXT]
                        const int* __restrict__ cnt_map,    // [B,MAXT]
                        float* __restrict__ out)            // [B,MAXT,D]
{
    const int b = blockIdx.x;             // [0, B*MAXT)
    const int i = b / MAXT;
    const int t = threadIdx.x;

    v4f* outp = (v4f*)(out + (size_t)b * ND);

    const int g = __builtin_amdgcn_readfirstlane(src_map[b]);   // scalar
    if (g < 0) {
        v4f z = {0.f, 0.f, 0.f, 0.f};
        __builtin_nontemporal_store(z, &outp[t]);
        return;
    }

    const int start = __builtin_amdgcn_readfirstlane(pr[i * 2 + 0]);
    const int end   = __builtin_amdgcn_readfirstlane(pr[i * 2 + 1]);
    const int cnt   = __builtin_amdgcn_readfirstlane(cnt_map[b]);

    const float* hb = h + (size_t)i * NS * ND;

    // 9 scalar row indices -> 9 SGPR row bases; loads issue independently.
    v4f acc = {0.f, 0.f, 0.f, 0.f};
#pragma unroll
    for (int k = 0; k < NK; ++k) {
        int v = __builtin_amdgcn_readfirstlane(patch_idx[(i * NG + g) * NK + k]);
        int row = (v >= 0) ? (start + v) : (end + 1 + v);   // -1 wraps to last row
        const v4f* rp = (const v4f*)(hb + (size_t)row * ND);
        acc += rp[t];
    }

    const float inv = 1.0f / (float)(cnt > 1 ? cnt : 1);
    acc *= inv;
    __builtin_nontemporal_store(acc, &outp[t]);
}

// ---------------------------------------------------------------------------
extern "C" void kernel_launch(void* const* d_in, const int* in_sizes, int n_in,
                              void* d_out, int out_size, void* d_ws, size_t ws_size,
                              hipStream_t stream)
{
    const float* h    = (const float*)d_in[0];   // hidden_states [B,S,D] f32
    // d_in[1] attention_mask (unused), d_in[2] image_grid_thw (unused)
    const int* pr     = (const int*)d_in[3];     // patch_range_list [B,2]
    const int* pidx   = (const int*)d_in[4];     // patch_indices_list_list [B,G,K]
    const int* rem    = (const int*)d_in[5];     // remove_index_list_list [B,R]

    float* out      = (float*)d_out;                         // [B,MAXT,D]
    float* attn_out = out + (size_t)NB * MAXT * ND;          // [B,MAXT] as f32

    int* src_map = (int*)d_ws;                               // [B*MAXT]
    int* cnt_map = src_map + NB * MAXT;                      // [B*MAXT]

    build_map_kernel<<<NB, 256, 0, stream>>>(pidx, rem, src_map, cnt_map, attn_out);
    gather_mean_kernel<<<NB * MAXT, 384, 0, stream>>>(h, pr, pidx, src_map, cnt_map, out);
}